// Round 17
// baseline (102.969 us; speedup 1.0000x reference)
//
#include <hip/hip_runtime.h>

typedef float f32x4 __attribute__((ext_vector_type(4)));
typedef short bf16x8 __attribute__((ext_vector_type(8)));
typedef unsigned short u16x8 __attribute__((ext_vector_type(8)));

__device__ __forceinline__ unsigned short f2bf(float x) {
  union { float f; unsigned u; } c; c.f = x;
  unsigned r = c.u + 0x7fffu + ((c.u >> 16) & 1u);
  return (unsigned short)(r >> 16);
}
__device__ __forceinline__ float bf2f(unsigned short v) {
  union { unsigned u; float f; } c; c.u = ((unsigned)v) << 16; return c.f;
}
__device__ __forceinline__ void gload_lds16(const void* g, void* l) {
  __builtin_amdgcn_global_load_lds((const __attribute__((address_space(1))) char*)g,
                                   (__attribute__((address_space(3))) char*)l, 16, 0, 0);
}

// 16-lane all-reduce via DPP (VALU pipe, no LDS shuffles).
__device__ __forceinline__ float dpp_max16(float x) {
  union { float f; int i; } a, b;
  a.f = x;
  b.i = __builtin_amdgcn_mov_dpp(a.i, 0xB1, 0xF, 0xF, true);  a.f = fmaxf(a.f, b.f);
  b.i = __builtin_amdgcn_mov_dpp(a.i, 0x4E, 0xF, 0xF, true);  a.f = fmaxf(a.f, b.f);
  b.i = __builtin_amdgcn_mov_dpp(a.i, 0x141, 0xF, 0xF, true); a.f = fmaxf(a.f, b.f);
  b.i = __builtin_amdgcn_mov_dpp(a.i, 0x140, 0xF, 0xF, true); a.f = fmaxf(a.f, b.f);
  return a.f;
}
__device__ __forceinline__ float dpp_sum16(float x) {
  union { float f; int i; } a, b;
  a.f = x;
  b.i = __builtin_amdgcn_mov_dpp(a.i, 0xB1, 0xF, 0xF, true);  a.f += b.f;
  b.i = __builtin_amdgcn_mov_dpp(a.i, 0x4E, 0xF, 0xF, true);  a.f += b.f;
  b.i = __builtin_amdgcn_mov_dpp(a.i, 0x141, 0xF, 0xF, true); a.f += b.f;
  b.i = __builtin_amdgcn_mov_dpp(a.i, 0x140, 0xF, 0xF, true); a.f += b.f;
  return a.f;
}

// ---------------------------------------------------------------------------
// Kernel 1: QKV projection (r13-proven).  LDS dbuf, one barrier per K-step.
// Q pre-scaled by 1/sqrt(32)*log2(e).  grid (256, 5), block 256.
// ---------------------------------------------------------------------------
__global__ __launch_bounds__(256) void qkv_proj(
    const float* __restrict__ x,
    const float* __restrict__ Wq, const float* __restrict__ bq,
    const float* __restrict__ Wk, const float* __restrict__ bk,
    const float* __restrict__ Wv, const float* __restrict__ bv,
    unsigned short* __restrict__ Qb, unsigned short* __restrict__ Kb,
    unsigned short* __restrict__ Vt)
{
  const int mb = blockIdx.x * 64;
  const int nb = blockIdx.y * 64;
  const int t = threadIdx.x;
  const int w = t >> 6, l = t & 63, g = l >> 4, li = l & 15;

  __shared__ __align__(16) unsigned short lds_a[2][4 * 64 * 8];
  __shared__ __align__(16) unsigned short lds_b[2][4 * 64 * 8];

  f32x4 acc[4];
#pragma unroll
  for (int ct = 0; ct < 4; ++ct) acc[ct] = (f32x4){0.f, 0.f, 0.f, 0.f};

  const int colw = nb + 16 * w + li;
  const float* Wsrc; int ldw, c0;
  if (colw < 32)      { Wsrc = Wq; ldw = 32;  c0 = colw; }
  else if (colw < 64) { Wsrc = Wk; ldw = 32;  c0 = colw - 32; }
  else                { Wsrc = Wv; ldw = 256; c0 = colw - 64; }

  const float* xsrc = x + (size_t)(mb + 16 * w + li) * 256 + 8 * g;

  float4 ra0 = *reinterpret_cast<const float4*>(xsrc);
  float4 ra1 = *reinterpret_cast<const float4*>(xsrc + 4);
  float rw[8];
#pragma unroll
  for (int j = 0; j < 8; ++j) rw[j] = Wsrc[(8 * g + j) * ldw + c0];

  for (int it = 0; it < 8; ++it) {
    const int cur = it & 1;
    {
      u16x8 u;
      u[0] = f2bf(ra0.x); u[1] = f2bf(ra0.y); u[2] = f2bf(ra0.z); u[3] = f2bf(ra0.w);
      u[4] = f2bf(ra1.x); u[5] = f2bf(ra1.y); u[6] = f2bf(ra1.z); u[7] = f2bf(ra1.w);
      *reinterpret_cast<u16x8*>(&lds_a[cur][(w * 64 + l) * 8]) = u;
      u16x8 v;
#pragma unroll
      for (int j = 0; j < 8; ++j) v[j] = f2bf(rw[j]);
      *reinterpret_cast<u16x8*>(&lds_b[cur][(w * 64 + l) * 8]) = v;
    }
    if (it < 7) {
      const int k0 = (it + 1) * 32;
      ra0 = *reinterpret_cast<const float4*>(xsrc + k0);
      ra1 = *reinterpret_cast<const float4*>(xsrc + k0 + 4);
#pragma unroll
      for (int j = 0; j < 8; ++j) rw[j] = Wsrc[(k0 + 8 * g + j) * ldw + c0];
    }
    __syncthreads();
    const bf16x8 af = *reinterpret_cast<const bf16x8*>(&lds_a[cur][(w * 64 + l) * 8]);
#pragma unroll
    for (int ct = 0; ct < 4; ++ct) {
      const bf16x8 bf = *reinterpret_cast<const bf16x8*>(&lds_b[cur][(ct * 64 + l) * 8]);
      acc[ct] = __builtin_amdgcn_mfma_f32_16x16x32_bf16(af, bf, acc[ct], 0, 0, 0);
    }
  }

  const float SC = 0.17677669529663688f * 1.44269504088896340f;
#pragma unroll
  for (int ct = 0; ct < 4; ++ct) {
#pragma unroll
    for (int r = 0; r < 4; ++r) {
      const int row = mb + 16 * w + 4 * g + r;
      const int col = nb + 16 * ct + li;
      float v = acc[ct][r];
      if (col < 32) {
        Qb[(size_t)row * 32 + col] = f2bf((v + bq[col]) * SC);
      } else if (col < 64) {
        Kb[(size_t)row * 32 + (col - 32)] = f2bf(v + bk[col - 32]);
      } else {
        const int c = col - 64;
        Vt[((size_t)((row >> 12) * 256 + c)) * 4096 + (row & 4095)] = f2bf(v + bv[c]);
      }
    }
  }
}

// ---------------------------------------------------------------------------
// Kernel 2: flash attention (r9/13/14 body) with XCD-grouped 1D grid:
// all 32 Q-blocks of one (batch,split) combo land on the SAME XCD so the
// shared K/V panel stays L2-resident (per-XCD set ~1.2MB < 4MB).
// Mapping: lin = xcd + 8*k; ncombo = 4S.
//   ncombo>=8:  combo = xcd + 8*(k>>5), j = k&31
//   ncombo==4:  combo = xcd&3,          j = (k & 15) + 16*(xcd>>2)
// ---------------------------------------------------------------------------
template <int S>
__global__ __launch_bounds__(512, 4) void attn_fwd(
    const unsigned short* __restrict__ Qb, const unsigned short* __restrict__ Kb,
    const unsigned short* __restrict__ Vt,
    unsigned short* __restrict__ Opart, float* __restrict__ Mpart,
    float* __restrict__ Lpart)
{
  constexpr int N = 4096;
  constexpr int SPAN = N / S;
  constexpr int NT = SPAN / 64;
  constexpr float THR = 8.0f;

  // ---- XCD-grouped block decode
  const int lin = blockIdx.x;
  const int xcd = lin & 7;
  const int k   = lin >> 3;
  int combo, j;
  if constexpr (4 * S >= 8) {
    combo = xcd + 8 * (k >> 5);
    j = k & 31;
  } else {  // S == 1: 4 combos across 8 XCDs (2 XCDs per combo)
    combo = xcd & 3;
    j = (k & 15) + 16 * (xcd >> 2);
  }
  const int qb = j * 128;
  const int b  = combo & 3;
  const int sp = combo >> 2;

  const int t = threadIdx.x;
  const int w = t >> 6, l = t & 63, g = (l >> 4), li = l & 15;
  const int wr = w >> 2, wc = w & 3;

  __shared__ __align__(16) int4 lds_k4[2][256];          // 8KB  K dbuf (64x32)
  __shared__ __align__(16) int4 lds_v4[2048];            // 32KB V tile (64x256)
  __shared__ __align__(16) unsigned short lds_p[8192];   // 16KB P (128x64)
  __shared__ float lds_alpha[128];
  __shared__ int lds_need[8];

  const bf16x8 qf = *reinterpret_cast<const bf16x8*>(
      Qb + ((size_t)(b * N + qb + 16 * w + li)) * 32 + 8 * g);

  const int jt0 = sp * SPAN;
  const unsigned short* baseK = Kb + ((size_t)(b * N + jt0 + 16 * w + li)) * 32 + 8 * g;
  const unsigned short* baseV = Vt + ((size_t)(b * 256 + li)) * N + jt0 + 8 * g;
  int offV[4];
#pragma unroll
  for (int ii = 0; ii < 4; ++ii) {
    const int p = w * 4 + ii;  // p = ctg*2+ks
    offV[ii] = ((p >> 1) * 16) * N + (p & 1) * 32;
  }

  f32x4 o[4][4];
#pragma unroll
  for (int rt = 0; rt < 4; ++rt)
#pragma unroll
    for (int ct = 0; ct < 4; ++ct) o[rt][ct] = (f32x4){0.f, 0.f, 0.f, 0.f};

  float mreg[4], lregp[4];
#pragma unroll
  for (int r = 0; r < 4; ++r) { mreg[r] = -1e30f; lregp[r] = 0.f; }

  // ---- prologue: K(0) -> buf0
  if (w < 4) gload_lds16(baseK, &lds_k4[0][w * 64]);
  __syncthreads();

  for (int tt = 0; tt < NT; ++tt) {
    const int cur = tt & 1;
    const int jt = tt * 64;
    // ---- issue V(tt) and K(tt+1); both drain at barrier1 (~full phase away)
#pragma unroll
    for (int ii = 0; ii < 4; ++ii)
      gload_lds16(baseV + offV[ii] + jt, &lds_v4[(w * 4 + ii) * 64]);
    if (w < 4 && tt + 1 < NT)
      gload_lds16(baseK + (size_t)(jt + 64) * 32, &lds_k4[cur ^ 1][w * 64]);

    // ---- QK^T from K buf[cur]
    f32x4 s[4];
    const f32x4 z = (f32x4){0.f, 0.f, 0.f, 0.f};
    __builtin_amdgcn_s_setprio(1);
#pragma unroll
    for (int ct = 0; ct < 4; ++ct) {
      const bf16x8 kf = *reinterpret_cast<const bf16x8*>(&lds_k4[cur][ct * 64 + l]);
      s[ct] = __builtin_amdgcn_mfma_f32_16x16x32_bf16(qf, kf, z, 0, 0, 0);
    }
    __builtin_amdgcn_s_setprio(0);

    // ---- gated defer-max
    float alpha[4];
    bool need = false;
#pragma unroll
    for (int r = 0; r < 4; ++r) {
      const float lm = fmaxf(fmaxf(s[0][r], s[1][r]), fmaxf(s[2][r], s[3][r]));
      need = need || (lm > mreg[r] + THR);
    }
    const bool wneed = (__ballot(need) != 0ull);
    if (wneed) {
#pragma unroll
      for (int r = 0; r < 4; ++r) {
        const float mx = dpp_max16(fmaxf(fmaxf(s[0][r], s[1][r]), fmaxf(s[2][r], s[3][r])));
        const float mn = fmaxf(mreg[r], mx);
        alpha[r] = __builtin_amdgcn_exp2f(mreg[r] - mn);
        mreg[r] = mn;
        lregp[r] *= alpha[r];
      }
    } else {
#pragma unroll
      for (int r = 0; r < 4; ++r) alpha[r] = 1.0f;
    }

    // ---- P = exp2(s - m); lane-partial row sums
    unsigned short pb[4][4];
#pragma unroll
    for (int ct = 0; ct < 4; ++ct)
#pragma unroll
      for (int r = 0; r < 4; ++r) {
        const float p = __builtin_amdgcn_exp2f(s[ct][r] - mreg[r]);
        lregp[r] += p;
        pb[ct][r] = f2bf(p);
      }

    if (l == 0) lds_need[w] = wneed ? 1 : 0;
    {
      const float asel = (li == 0) ? alpha[0] : ((li == 1) ? alpha[1]
                       : ((li == 2) ? alpha[2] : alpha[3]));
      if (li < 4) lds_alpha[16 * w + 4 * g + li] = asel;
    }
    // ---- P -> LDS in MFMA-A fragment layout
#pragma unroll
    for (int ct = 0; ct < 4; ++ct)
#pragma unroll
      for (int r = 0; r < 4; ++r) {
        const int idx = ((w * 2 + (ct >> 1)) * 64 +
                         (2 * (ct & 1) + (li >> 3)) * 16 + 4 * g + r) * 8 + (li & 7);
        lds_p[idx] = pb[ct][r];
      }
    __syncthreads();  // barrier1: drains V(tt)/K(tt+1) DMA, publishes P

    // ---- conditional O rescale
    const int needAny = lds_need[4 * wr] | lds_need[4 * wr + 1] |
                        lds_need[4 * wr + 2] | lds_need[4 * wr + 3];
    if (needAny) {
#pragma unroll
      for (int rt = 0; rt < 4; ++rt) {
        const float a0 = lds_alpha[64 * wr + 16 * rt + 4 * g + 0];
        const float a1 = lds_alpha[64 * wr + 16 * rt + 4 * g + 1];
        const float a2 = lds_alpha[64 * wr + 16 * rt + 4 * g + 2];
        const float a3 = lds_alpha[64 * wr + 16 * rt + 4 * g + 3];
#pragma unroll
        for (int ct = 0; ct < 4; ++ct) {
          o[rt][ct][0] *= a0; o[rt][ct][1] *= a1;
          o[rt][ct][2] *= a2; o[rt][ct][3] *= a3;
        }
      }
    }
    // ---- PV
    __builtin_amdgcn_s_setprio(1);
#pragma unroll
    for (int ks = 0; ks < 2; ++ks) {
      bf16x8 vf[4], pf[4];
#pragma unroll
      for (int ct = 0; ct < 4; ++ct)
        vf[ct] = *reinterpret_cast<const bf16x8*>(&lds_v4[((4 * wc + ct) * 2 + ks) * 64 + l]);
#pragma unroll
      for (int rt = 0; rt < 4; ++rt)
        pf[rt] = *reinterpret_cast<const bf16x8*>(
            &lds_p[(((4 * wr + rt) * 2 + ks) * 64 + l) * 8]);
#pragma unroll
      for (int rt = 0; rt < 4; ++rt)
#pragma unroll
        for (int ct = 0; ct < 4; ++ct)
          o[rt][ct] = __builtin_amdgcn_mfma_f32_16x16x32_bf16(pf[rt], vf[ct], o[rt][ct], 0, 0, 0);
    }
    __builtin_amdgcn_s_setprio(0);
    __syncthreads();  // barrier2: protect P/V for next tile
  }

  // ---- final l reduction, per-row m,l partials
  {
    const size_t mlbase = ((size_t)(sp * 4 + b)) * N + qb + 16 * w + 4 * g;
    float lreg[4];
#pragma unroll
    for (int r = 0; r < 4; ++r) lreg[r] = dpp_sum16(lregp[r]);
    const float msel = (li == 0) ? mreg[0] : ((li == 1) ? mreg[1]
                     : ((li == 2) ? mreg[2] : mreg[3]));
    const float lsel = (li == 0) ? lreg[0] : ((li == 1) ? lreg[1]
                     : ((li == 2) ? lreg[2] : lreg[3]));
    if (li < 4) {
      Mpart[mlbase + li] = msel;
      Lpart[mlbase + li] = lsel;
    }
  }

  // ---- O epilogue: UNNORMALIZED, transpose through LDS (reuse V buf), store
  unsigned short* po = reinterpret_cast<unsigned short*>(lds_v4);
#pragma unroll
  for (int pass = 0; pass < 2; ++pass) {
    if (wr == pass) {
#pragma unroll
      for (int rt = 0; rt < 4; ++rt) {
#pragma unroll
        for (int ct = 0; ct < 4; ++ct) {
          const int col = 64 * wc + 16 * ct + li;
          po[(16 * rt + 4 * g + 0) * 256 + col] = f2bf(o[rt][ct][0]);
          po[(16 * rt + 4 * g + 1) * 256 + col] = f2bf(o[rt][ct][1]);
          po[(16 * rt + 4 * g + 2) * 256 + col] = f2bf(o[rt][ct][2]);
          po[(16 * rt + 4 * g + 3) * 256 + col] = f2bf(o[rt][ct][3]);
        }
      }
    }
    __syncthreads();
    int4* dst = reinterpret_cast<int4*>(
        Opart + ((size_t)((sp * 4 + b)) * N + qb + pass * 64) * 256);
    const int4* src = reinterpret_cast<const int4*>(po);
#pragma unroll
    for (int ii = 0; ii < 4; ++ii) dst[ii * 512 + t] = src[ii * 512 + t];
    __syncthreads();
  }
}

// ---------------------------------------------------------------------------
// Kernel 3a: split-combine, ONE pass (r14-proven).  grid 2048, block 256.
// ---------------------------------------------------------------------------
template <int S>
__global__ __launch_bounds__(256) void combine_o(
    const unsigned short* __restrict__ Opart, const float* __restrict__ Mpart,
    const float* __restrict__ Lpart, unsigned short* __restrict__ Oc)
{
  const int idx = blockIdx.x * 256 + threadIdx.x;
  const int tok = idx >> 5;
  const int ch  = idx & 31;
  const int b = tok >> 12, n = tok & 4095;

  float m[S], lv[S];
#pragma unroll
  for (int s = 0; s < S; ++s) {
    m[s]  = Mpart[((size_t)(s * 4 + b)) * 4096 + n];
    lv[s] = Lpart[((size_t)(s * 4 + b)) * 4096 + n];
  }
  float M = m[0];
#pragma unroll
  for (int s = 1; s < S; ++s) M = fmaxf(M, m[s]);
  float wv[S], L = 0.f;
#pragma unroll
  for (int s = 0; s < S; ++s) { wv[s] = __builtin_amdgcn_exp2f(m[s] - M); L += wv[s] * lv[s]; }
  const float inv = 1.f / L;

  float a8[8];
#pragma unroll
  for (int j = 0; j < 8; ++j) a8[j] = 0.f;
#pragma unroll
  for (int s = 0; s < S; ++s) {
    const u16x8 raw = *reinterpret_cast<const u16x8*>(
        Opart + (((size_t)(s * 4 + b)) * 4096 + n) * 256 + ch * 8);
    const float wt = wv[s] * inv;
#pragma unroll
    for (int j = 0; j < 8; ++j) a8[j] += wt * bf2f(raw[j]);
  }
  u16x8 u;
#pragma unroll
  for (int j = 0; j < 8; ++j) u[j] = f2bf(a8[j]);
  *reinterpret_cast<u16x8*>(Oc + (size_t)tok * 256 + ch * 8) = u;
}

// ---------------------------------------------------------------------------
// Kernel 3b: output projection + residual (r14-proven).  grid (256,4), 256.
// ---------------------------------------------------------------------------
__global__ __launch_bounds__(256) void out_proj(
    const unsigned short* __restrict__ Oc,
    const float* __restrict__ Wp, const float* __restrict__ bp,
    const float* __restrict__ x, const float* __restrict__ gptr,
    float* __restrict__ y)
{
  const int mb = blockIdx.x * 64;
  const int nb = blockIdx.y * 64;
  const int t = threadIdx.x;
  const int w = t >> 6, l = t & 63, g = l >> 4, li = l & 15;

  __shared__ __align__(16) unsigned short lds_a[2][4 * 64 * 8];
  __shared__ __align__(16) unsigned short lds_b[2][4 * 64 * 8];

  const unsigned short* osrc = Oc + (size_t)(mb + 16 * w + li) * 256 + 8 * g;
  const int colw = nb + 16 * w + li;

  f32x4 acc[4];
#pragma unroll
  for (int ct = 0; ct < 4; ++ct) acc[ct] = (f32x4){0.f, 0.f, 0.f, 0.f};

  u16x8 rraw = *reinterpret_cast<const u16x8*>(osrc);
  float rw[8];
#pragma unroll
  for (int j = 0; j < 8; ++j) rw[j] = Wp[(8 * g + j) * 256 + colw];

  for (int it = 0; it < 8; ++it) {
    const int cur = it & 1;
    {
      *reinterpret_cast<u16x8*>(&lds_a[cur][(w * 64 + l) * 8]) = rraw;
      u16x8 v;
#pragma unroll
      for (int j = 0; j < 8; ++j) v[j] = f2bf(rw[j]);
      *reinterpret_cast<u16x8*>(&lds_b[cur][(w * 64 + l) * 8]) = v;
    }
    if (it < 7) {
      const int k0 = (it + 1) * 32;
      rraw = *reinterpret_cast<const u16x8*>(osrc + k0);
#pragma unroll
      for (int j = 0; j < 8; ++j) rw[j] = Wp[(k0 + 8 * g + j) * 256 + colw];
    }
    __syncthreads();
    const bf16x8 af = *reinterpret_cast<const bf16x8*>(&lds_a[cur][(w * 64 + l) * 8]);
#pragma unroll
    for (int ct = 0; ct < 4; ++ct) {
      const bf16x8 bf = *reinterpret_cast<const bf16x8*>(&lds_b[cur][(ct * 64 + l) * 8]);
      acc[ct] = __builtin_amdgcn_mfma_f32_16x16x32_bf16(af, bf, acc[ct], 0, 0, 0);
    }
  }

  const float gamma = gptr[0];
#pragma unroll
  for (int ct = 0; ct < 4; ++ct) {
#pragma unroll
    for (int r = 0; r < 4; ++r) {
      const int row = mb + 16 * w + 4 * g + r;
      const int col = nb + 16 * ct + li;
      const size_t idx = (size_t)row * 256 + col;
      y[idx] = x[idx] + gamma * (acc[ct][r] + bp[col]);
    }
  }
}

extern "C" void kernel_launch(void* const* d_in, const int* in_sizes, int n_in,
                              void* d_out, int out_size, void* d_ws, size_t ws_size,
                              hipStream_t stream) {
  const float* x  = (const float*)d_in[0];
  const float* Wq = (const float*)d_in[1];
  const float* bq = (const float*)d_in[2];
  const float* Wk = (const float*)d_in[3];
  const float* bk = (const float*)d_in[4];
  const float* Wv = (const float*)d_in[5];
  const float* bv = (const float*)d_in[6];
  const float* Wp = (const float*)d_in[7];
  const float* bp = (const float*)d_in[8];
  const float* gm = (const float*)d_in[9];
  float* y = (float*)d_out;

  unsigned short* Qb = (unsigned short*)d_ws;
  unsigned short* Kb = Qb + (size_t)4 * 4096 * 32;
  unsigned short* Vt = Kb + (size_t)4 * 4096 * 32;
  unsigned short* Op = Vt + (size_t)4 * 256 * 4096;
  const size_t base_bytes = ((size_t)4 * 4096 * 32 * 2 + (size_t)4 * 256 * 4096) * 2;

  qkv_proj<<<dim3(256, 5), 256, 0, stream>>>(x, Wq, bq, Wk, bk, Wv, bv, Qb, Kb, Vt);

  const size_t per_split = (size_t)4 * 4096 * 256 * 2 + (size_t)4 * 4096 * 4 * 2;
  int S = 1;
  if (ws_size >= base_bytes + 4 * per_split) S = 4;
  else if (ws_size >= base_bytes + 2 * per_split) S = 2;

  unsigned short* Oc = Vt;  // dead after attn; 8MB exactly

  if (S == 4) {
    float* Mp = (float*)(Op + (size_t)4 * 4 * 4096 * 256);
    float* Lp = Mp + (size_t)4 * 4 * 4096;
    attn_fwd<4><<<512, 512, 0, stream>>>(Qb, Kb, Vt, Op, Mp, Lp);
    combine_o<4><<<2048, 256, 0, stream>>>(Op, Mp, Lp, Oc);
  } else if (S == 2) {
    float* Mp = (float*)(Op + (size_t)2 * 4 * 4096 * 256);
    float* Lp = Mp + (size_t)2 * 4 * 4096;
    attn_fwd<2><<<256, 512, 0, stream>>>(Qb, Kb, Vt, Op, Mp, Lp);
    combine_o<2><<<2048, 256, 0, stream>>>(Op, Mp, Lp, Oc);
  } else {
    float* Mp = (float*)(Op + (size_t)1 * 4 * 4096 * 256);
    float* Lp = Mp + (size_t)1 * 4 * 4096;
    attn_fwd<1><<<128, 512, 0, stream>>>(Qb, Kb, Vt, Op, Mp, Lp);
    combine_o<1><<<2048, 256, 0, stream>>>(Op, Mp, Lp, Oc);
  }
  out_proj<<<dim3(256, 4), 256, 0, stream>>>(Oc, Wp, bp, x, gm, y);
}

// Round 18
// 96.645 us; speedup vs baseline: 1.0654x; 1.0654x over previous
//
#include <hip/hip_runtime.h>

typedef float f32x4 __attribute__((ext_vector_type(4)));
typedef short bf16x8 __attribute__((ext_vector_type(8)));
typedef unsigned short u16x8 __attribute__((ext_vector_type(8)));

__device__ __forceinline__ unsigned short f2bf(float x) {
  union { float f; unsigned u; } c; c.f = x;
  unsigned r = c.u + 0x7fffu + ((c.u >> 16) & 1u);
  return (unsigned short)(r >> 16);
}
__device__ __forceinline__ float bf2f(unsigned short v) {
  union { unsigned u; float f; } c; c.u = ((unsigned)v) << 16; return c.f;
}
__device__ __forceinline__ void gload_lds16(const void* g, void* l) {
  __builtin_amdgcn_global_load_lds((const __attribute__((address_space(1))) char*)g,
                                   (__attribute__((address_space(3))) char*)l, 16, 0, 0);
}

// 16-lane all-reduce via DPP (VALU pipe, no LDS shuffles).
__device__ __forceinline__ float dpp_max16(float x) {
  union { float f; int i; } a, b;
  a.f = x;
  b.i = __builtin_amdgcn_mov_dpp(a.i, 0xB1, 0xF, 0xF, true);  a.f = fmaxf(a.f, b.f);
  b.i = __builtin_amdgcn_mov_dpp(a.i, 0x4E, 0xF, 0xF, true);  a.f = fmaxf(a.f, b.f);
  b.i = __builtin_amdgcn_mov_dpp(a.i, 0x141, 0xF, 0xF, true); a.f = fmaxf(a.f, b.f);
  b.i = __builtin_amdgcn_mov_dpp(a.i, 0x140, 0xF, 0xF, true); a.f = fmaxf(a.f, b.f);
  return a.f;
}
__device__ __forceinline__ float dpp_sum16(float x) {
  union { float f; int i; } a, b;
  a.f = x;
  b.i = __builtin_amdgcn_mov_dpp(a.i, 0xB1, 0xF, 0xF, true);  a.f += b.f;
  b.i = __builtin_amdgcn_mov_dpp(a.i, 0x4E, 0xF, 0xF, true);  a.f += b.f;
  b.i = __builtin_amdgcn_mov_dpp(a.i, 0x141, 0xF, 0xF, true); a.f += b.f;
  b.i = __builtin_amdgcn_mov_dpp(a.i, 0x140, 0xF, 0xF, true); a.f += b.f;
  return a.f;
}

// ---------------------------------------------------------------------------
// Kernel 1: QKV projection (r13-proven).  LDS dbuf, one barrier per K-step.
// Q pre-scaled by 1/sqrt(32)*log2(e).  grid (256, 5), block 256.
// ---------------------------------------------------------------------------
__global__ __launch_bounds__(256) void qkv_proj(
    const float* __restrict__ x,
    const float* __restrict__ Wq, const float* __restrict__ bq,
    const float* __restrict__ Wk, const float* __restrict__ bk,
    const float* __restrict__ Wv, const float* __restrict__ bv,
    unsigned short* __restrict__ Qb, unsigned short* __restrict__ Kb,
    unsigned short* __restrict__ Vt)
{
  const int mb = blockIdx.x * 64;
  const int nb = blockIdx.y * 64;
  const int t = threadIdx.x;
  const int w = t >> 6, l = t & 63, g = l >> 4, li = l & 15;

  __shared__ __align__(16) unsigned short lds_a[2][4 * 64 * 8];
  __shared__ __align__(16) unsigned short lds_b[2][4 * 64 * 8];

  f32x4 acc[4];
#pragma unroll
  for (int ct = 0; ct < 4; ++ct) acc[ct] = (f32x4){0.f, 0.f, 0.f, 0.f};

  const int colw = nb + 16 * w + li;
  const float* Wsrc; int ldw, c0;
  if (colw < 32)      { Wsrc = Wq; ldw = 32;  c0 = colw; }
  else if (colw < 64) { Wsrc = Wk; ldw = 32;  c0 = colw - 32; }
  else                { Wsrc = Wv; ldw = 256; c0 = colw - 64; }

  const float* xsrc = x + (size_t)(mb + 16 * w + li) * 256 + 8 * g;

  float4 ra0 = *reinterpret_cast<const float4*>(xsrc);
  float4 ra1 = *reinterpret_cast<const float4*>(xsrc + 4);
  float rw[8];
#pragma unroll
  for (int j = 0; j < 8; ++j) rw[j] = Wsrc[(8 * g + j) * ldw + c0];

  for (int it = 0; it < 8; ++it) {
    const int cur = it & 1;
    {
      u16x8 u;
      u[0] = f2bf(ra0.x); u[1] = f2bf(ra0.y); u[2] = f2bf(ra0.z); u[3] = f2bf(ra0.w);
      u[4] = f2bf(ra1.x); u[5] = f2bf(ra1.y); u[6] = f2bf(ra1.z); u[7] = f2bf(ra1.w);
      *reinterpret_cast<u16x8*>(&lds_a[cur][(w * 64 + l) * 8]) = u;
      u16x8 v;
#pragma unroll
      for (int j = 0; j < 8; ++j) v[j] = f2bf(rw[j]);
      *reinterpret_cast<u16x8*>(&lds_b[cur][(w * 64 + l) * 8]) = v;
    }
    if (it < 7) {
      const int k0 = (it + 1) * 32;
      ra0 = *reinterpret_cast<const float4*>(xsrc + k0);
      ra1 = *reinterpret_cast<const float4*>(xsrc + k0 + 4);
#pragma unroll
      for (int j = 0; j < 8; ++j) rw[j] = Wsrc[(k0 + 8 * g + j) * ldw + c0];
    }
    __syncthreads();
    const bf16x8 af = *reinterpret_cast<const bf16x8*>(&lds_a[cur][(w * 64 + l) * 8]);
#pragma unroll
    for (int ct = 0; ct < 4; ++ct) {
      const bf16x8 bf = *reinterpret_cast<const bf16x8*>(&lds_b[cur][(ct * 64 + l) * 8]);
      acc[ct] = __builtin_amdgcn_mfma_f32_16x16x32_bf16(af, bf, acc[ct], 0, 0, 0);
    }
  }

  const float SC = 0.17677669529663688f * 1.44269504088896340f;
#pragma unroll
  for (int ct = 0; ct < 4; ++ct) {
#pragma unroll
    for (int r = 0; r < 4; ++r) {
      const int row = mb + 16 * w + 4 * g + r;
      const int col = nb + 16 * ct + li;
      float v = acc[ct][r];
      if (col < 32) {
        Qb[(size_t)row * 32 + col] = f2bf((v + bq[col]) * SC);
      } else if (col < 64) {
        Kb[(size_t)row * 32 + (col - 32)] = f2bf(v + bk[col - 32]);
      } else {
        const int c = col - 64;
        Vt[((size_t)((row >> 12) * 256 + c)) * 4096 + (row & 4095)] = f2bf(v + bv[c]);
      }
    }
  }
}

// ---------------------------------------------------------------------------
// Kernel 2: flash attention (the proven round-9/13/14 kernel, unchanged).
// ---------------------------------------------------------------------------
template <int S>
__global__ __launch_bounds__(512, 4) void attn_fwd(
    const unsigned short* __restrict__ Qb, const unsigned short* __restrict__ Kb,
    const unsigned short* __restrict__ Vt,
    unsigned short* __restrict__ Opart, float* __restrict__ Mpart,
    float* __restrict__ Lpart)
{
  constexpr int N = 4096;
  constexpr int SPAN = N / S;
  constexpr int NT = SPAN / 64;
  constexpr float THR = 8.0f;
  const int qb = blockIdx.x * 128;
  const int b  = blockIdx.y;
  const int sp = blockIdx.z;
  const int t = threadIdx.x;
  const int w = t >> 6, l = t & 63, g = (l >> 4), li = l & 15;
  const int wr = w >> 2, wc = w & 3;

  __shared__ __align__(16) int4 lds_k4[2][256];          // 8KB  K dbuf (64x32)
  __shared__ __align__(16) int4 lds_v4[2048];            // 32KB V tile (64x256)
  __shared__ __align__(16) unsigned short lds_p[8192];   // 16KB P (128x64)
  __shared__ float lds_alpha[128];
  __shared__ int lds_need[8];

  const bf16x8 qf = *reinterpret_cast<const bf16x8*>(
      Qb + ((size_t)(b * N + qb + 16 * w + li)) * 32 + 8 * g);

  const int jt0 = sp * SPAN;
  const unsigned short* baseK = Kb + ((size_t)(b * N + jt0 + 16 * w + li)) * 32 + 8 * g;
  const unsigned short* baseV = Vt + ((size_t)(b * 256 + li)) * N + jt0 + 8 * g;
  int offV[4];
#pragma unroll
  for (int ii = 0; ii < 4; ++ii) {
    const int p = w * 4 + ii;  // p = ctg*2+ks
    offV[ii] = ((p >> 1) * 16) * N + (p & 1) * 32;
  }

  f32x4 o[4][4];
#pragma unroll
  for (int rt = 0; rt < 4; ++rt)
#pragma unroll
    for (int ct = 0; ct < 4; ++ct) o[rt][ct] = (f32x4){0.f, 0.f, 0.f, 0.f};

  float mreg[4], lregp[4];
#pragma unroll
  for (int r = 0; r < 4; ++r) { mreg[r] = -1e30f; lregp[r] = 0.f; }

  // ---- prologue: K(0) -> buf0
  if (w < 4) gload_lds16(baseK, &lds_k4[0][w * 64]);
  __syncthreads();

  for (int tt = 0; tt < NT; ++tt) {
    const int cur = tt & 1;
    const int jt = tt * 64;
    // ---- issue V(tt) and K(tt+1); both drain at barrier1 (~full phase away)
#pragma unroll
    for (int ii = 0; ii < 4; ++ii)
      gload_lds16(baseV + offV[ii] + jt, &lds_v4[(w * 4 + ii) * 64]);
    if (w < 4 && tt + 1 < NT)
      gload_lds16(baseK + (size_t)(jt + 64) * 32, &lds_k4[cur ^ 1][w * 64]);

    // ---- QK^T from K buf[cur]
    f32x4 s[4];
    const f32x4 z = (f32x4){0.f, 0.f, 0.f, 0.f};
    __builtin_amdgcn_s_setprio(1);
#pragma unroll
    for (int ct = 0; ct < 4; ++ct) {
      const bf16x8 kf = *reinterpret_cast<const bf16x8*>(&lds_k4[cur][ct * 64 + l]);
      s[ct] = __builtin_amdgcn_mfma_f32_16x16x32_bf16(qf, kf, z, 0, 0, 0);
    }
    __builtin_amdgcn_s_setprio(0);

    // ---- gated defer-max
    float alpha[4];
    bool need = false;
#pragma unroll
    for (int r = 0; r < 4; ++r) {
      const float lm = fmaxf(fmaxf(s[0][r], s[1][r]), fmaxf(s[2][r], s[3][r]));
      need = need || (lm > mreg[r] + THR);
    }
    const bool wneed = (__ballot(need) != 0ull);
    if (wneed) {
#pragma unroll
      for (int r = 0; r < 4; ++r) {
        const float mx = dpp_max16(fmaxf(fmaxf(s[0][r], s[1][r]), fmaxf(s[2][r], s[3][r])));
        const float mn = fmaxf(mreg[r], mx);
        alpha[r] = __builtin_amdgcn_exp2f(mreg[r] - mn);
        mreg[r] = mn;
        lregp[r] *= alpha[r];
      }
    } else {
#pragma unroll
      for (int r = 0; r < 4; ++r) alpha[r] = 1.0f;
    }

    // ---- P = exp2(s - m); lane-partial row sums
    unsigned short pb[4][4];
#pragma unroll
    for (int ct = 0; ct < 4; ++ct)
#pragma unroll
      for (int r = 0; r < 4; ++r) {
        const float p = __builtin_amdgcn_exp2f(s[ct][r] - mreg[r]);
        lregp[r] += p;
        pb[ct][r] = f2bf(p);
      }

    if (l == 0) lds_need[w] = wneed ? 1 : 0;
    {
      const float asel = (li == 0) ? alpha[0] : ((li == 1) ? alpha[1]
                       : ((li == 2) ? alpha[2] : alpha[3]));
      if (li < 4) lds_alpha[16 * w + 4 * g + li] = asel;
    }
    // ---- P -> LDS in MFMA-A fragment layout
#pragma unroll
    for (int ct = 0; ct < 4; ++ct)
#pragma unroll
      for (int r = 0; r < 4; ++r) {
        const int idx = ((w * 2 + (ct >> 1)) * 64 +
                         (2 * (ct & 1) + (li >> 3)) * 16 + 4 * g + r) * 8 + (li & 7);
        lds_p[idx] = pb[ct][r];
      }
    __syncthreads();  // barrier1: drains V(tt)/K(tt+1) DMA, publishes P

    // ---- conditional O rescale
    const int needAny = lds_need[4 * wr] | lds_need[4 * wr + 1] |
                        lds_need[4 * wr + 2] | lds_need[4 * wr + 3];
    if (needAny) {
#pragma unroll
      for (int rt = 0; rt < 4; ++rt) {
        const float a0 = lds_alpha[64 * wr + 16 * rt + 4 * g + 0];
        const float a1 = lds_alpha[64 * wr + 16 * rt + 4 * g + 1];
        const float a2 = lds_alpha[64 * wr + 16 * rt + 4 * g + 2];
        const float a3 = lds_alpha[64 * wr + 16 * rt + 4 * g + 3];
#pragma unroll
        for (int ct = 0; ct < 4; ++ct) {
          o[rt][ct][0] *= a0; o[rt][ct][1] *= a1;
          o[rt][ct][2] *= a2; o[rt][ct][3] *= a3;
        }
      }
    }
    // ---- PV
    __builtin_amdgcn_s_setprio(1);
#pragma unroll
    for (int ks = 0; ks < 2; ++ks) {
      bf16x8 vf[4], pf[4];
#pragma unroll
      for (int ct = 0; ct < 4; ++ct)
        vf[ct] = *reinterpret_cast<const bf16x8*>(&lds_v4[((4 * wc + ct) * 2 + ks) * 64 + l]);
#pragma unroll
      for (int rt = 0; rt < 4; ++rt)
        pf[rt] = *reinterpret_cast<const bf16x8*>(
            &lds_p[(((4 * wr + rt) * 2 + ks) * 64 + l) * 8]);
#pragma unroll
      for (int rt = 0; rt < 4; ++rt)
#pragma unroll
        for (int ct = 0; ct < 4; ++ct)
          o[rt][ct] = __builtin_amdgcn_mfma_f32_16x16x32_bf16(pf[rt], vf[ct], o[rt][ct], 0, 0, 0);
    }
    __builtin_amdgcn_s_setprio(0);
    __syncthreads();  // barrier2: protect P/V for next tile
  }

  // ---- final l reduction, per-row m,l partials
  {
    const size_t mlbase = ((size_t)(sp * 4 + b)) * N + qb + 16 * w + 4 * g;
    float lreg[4];
#pragma unroll
    for (int r = 0; r < 4; ++r) lreg[r] = dpp_sum16(lregp[r]);
    const float msel = (li == 0) ? mreg[0] : ((li == 1) ? mreg[1]
                     : ((li == 2) ? mreg[2] : mreg[3]));
    const float lsel = (li == 0) ? lreg[0] : ((li == 1) ? lreg[1]
                     : ((li == 2) ? lreg[2] : lreg[3]));
    if (li < 4) {
      Mpart[mlbase + li] = msel;
      Lpart[mlbase + li] = lsel;
    }
  }

  // ---- O epilogue: UNNORMALIZED, transpose through LDS (reuse V buf), store
  unsigned short* po = reinterpret_cast<unsigned short*>(lds_v4);
#pragma unroll
  for (int pass = 0; pass < 2; ++pass) {
    if (wr == pass) {
#pragma unroll
      for (int rt = 0; rt < 4; ++rt) {
#pragma unroll
        for (int ct = 0; ct < 4; ++ct) {
          const int col = 64 * wc + 16 * ct + li;
          po[(16 * rt + 4 * g + 0) * 256 + col] = f2bf(o[rt][ct][0]);
          po[(16 * rt + 4 * g + 1) * 256 + col] = f2bf(o[rt][ct][1]);
          po[(16 * rt + 4 * g + 2) * 256 + col] = f2bf(o[rt][ct][2]);
          po[(16 * rt + 4 * g + 3) * 256 + col] = f2bf(o[rt][ct][3]);
        }
      }
    }
    __syncthreads();
    int4* dst = reinterpret_cast<int4*>(
        Opart + ((size_t)((sp * 4 + b)) * N + qb + pass * 64) * 256);
    const int4* src = reinterpret_cast<const int4*>(po);
#pragma unroll
    for (int ii = 0; ii < 4; ++ii) dst[ii * 512 + t] = src[ii * 512 + t];
    __syncthreads();
  }
}

// ---------------------------------------------------------------------------
// Kernel 3a: split-combine, ONE pass (r14-proven).  grid 2048, block 256.
// ---------------------------------------------------------------------------
template <int S>
__global__ __launch_bounds__(256) void combine_o(
    const unsigned short* __restrict__ Opart, const float* __restrict__ Mpart,
    const float* __restrict__ Lpart, unsigned short* __restrict__ Oc)
{
  const int idx = blockIdx.x * 256 + threadIdx.x;
  const int tok = idx >> 5;
  const int ch  = idx & 31;
  const int b = tok >> 12, n = tok & 4095;

  float m[S], lv[S];
#pragma unroll
  for (int s = 0; s < S; ++s) {
    m[s]  = Mpart[((size_t)(s * 4 + b)) * 4096 + n];
    lv[s] = Lpart[((size_t)(s * 4 + b)) * 4096 + n];
  }
  float M = m[0];
#pragma unroll
  for (int s = 1; s < S; ++s) M = fmaxf(M, m[s]);
  float wv[S], L = 0.f;
#pragma unroll
  for (int s = 0; s < S; ++s) { wv[s] = __builtin_amdgcn_exp2f(m[s] - M); L += wv[s] * lv[s]; }
  const float inv = 1.f / L;

  float a8[8];
#pragma unroll
  for (int j = 0; j < 8; ++j) a8[j] = 0.f;
#pragma unroll
  for (int s = 0; s < S; ++s) {
    const u16x8 raw = *reinterpret_cast<const u16x8*>(
        Opart + (((size_t)(s * 4 + b)) * 4096 + n) * 256 + ch * 8);
    const float wt = wv[s] * inv;
#pragma unroll
    for (int j = 0; j < 8; ++j) a8[j] += wt * bf2f(raw[j]);
  }
  u16x8 u;
#pragma unroll
  for (int j = 0; j < 8; ++j) u[j] = f2bf(a8[j]);
  *reinterpret_cast<u16x8*>(Oc + (size_t)tok * 256 + ch * 8) = u;
}

// ---------------------------------------------------------------------------
// Kernel 3b: output projection + residual (r14-proven).  grid (256,4), 256.
// ---------------------------------------------------------------------------
__global__ __launch_bounds__(256) void out_proj(
    const unsigned short* __restrict__ Oc,
    const float* __restrict__ Wp, const float* __restrict__ bp,
    const float* __restrict__ x, const float* __restrict__ gptr,
    float* __restrict__ y)
{
  const int mb = blockIdx.x * 64;
  const int nb = blockIdx.y * 64;
  const int t = threadIdx.x;
  const int w = t >> 6, l = t & 63, g = l >> 4, li = l & 15;

  __shared__ __align__(16) unsigned short lds_a[2][4 * 64 * 8];
  __shared__ __align__(16) unsigned short lds_b[2][4 * 64 * 8];

  const unsigned short* osrc = Oc + (size_t)(mb + 16 * w + li) * 256 + 8 * g;
  const int colw = nb + 16 * w + li;

  f32x4 acc[4];
#pragma unroll
  for (int ct = 0; ct < 4; ++ct) acc[ct] = (f32x4){0.f, 0.f, 0.f, 0.f};

  u16x8 rraw = *reinterpret_cast<const u16x8*>(osrc);
  float rw[8];
#pragma unroll
  for (int j = 0; j < 8; ++j) rw[j] = Wp[(8 * g + j) * 256 + colw];

  for (int it = 0; it < 8; ++it) {
    const int cur = it & 1;
    {
      *reinterpret_cast<u16x8*>(&lds_a[cur][(w * 64 + l) * 8]) = rraw;
      u16x8 v;
#pragma unroll
      for (int j = 0; j < 8; ++j) v[j] = f2bf(rw[j]);
      *reinterpret_cast<u16x8*>(&lds_b[cur][(w * 64 + l) * 8]) = v;
    }
    if (it < 7) {
      const int k0 = (it + 1) * 32;
      rraw = *reinterpret_cast<const u16x8*>(osrc + k0);
#pragma unroll
      for (int j = 0; j < 8; ++j) rw[j] = Wp[(k0 + 8 * g + j) * 256 + colw];
    }
    __syncthreads();
    const bf16x8 af = *reinterpret_cast<const bf16x8*>(&lds_a[cur][(w * 64 + l) * 8]);
#pragma unroll
    for (int ct = 0; ct < 4; ++ct) {
      const bf16x8 bf = *reinterpret_cast<const bf16x8*>(&lds_b[cur][(ct * 64 + l) * 8]);
      acc[ct] = __builtin_amdgcn_mfma_f32_16x16x32_bf16(af, bf, acc[ct], 0, 0, 0);
    }
  }

  const float gamma = gptr[0];
#pragma unroll
  for (int ct = 0; ct < 4; ++ct) {
#pragma unroll
    for (int r = 0; r < 4; ++r) {
      const int row = mb + 16 * w + 4 * g + r;
      const int col = nb + 16 * ct + li;
      const size_t idx = (size_t)row * 256 + col;
      y[idx] = x[idx] + gamma * (acc[ct][r] + bp[col]);
    }
  }
}

extern "C" void kernel_launch(void* const* d_in, const int* in_sizes, int n_in,
                              void* d_out, int out_size, void* d_ws, size_t ws_size,
                              hipStream_t stream) {
  const float* x  = (const float*)d_in[0];
  const float* Wq = (const float*)d_in[1];
  const float* bq = (const float*)d_in[2];
  const float* Wk = (const float*)d_in[3];
  const float* bk = (const float*)d_in[4];
  const float* Wv = (const float*)d_in[5];
  const float* bv = (const float*)d_in[6];
  const float* Wp = (const float*)d_in[7];
  const float* bp = (const float*)d_in[8];
  const float* gm = (const float*)d_in[9];
  float* y = (float*)d_out;

  unsigned short* Qb = (unsigned short*)d_ws;
  unsigned short* Kb = Qb + (size_t)4 * 4096 * 32;
  unsigned short* Vt = Kb + (size_t)4 * 4096 * 32;
  unsigned short* Op = Vt + (size_t)4 * 256 * 4096;
  const size_t base_bytes = ((size_t)4 * 4096 * 32 * 2 + (size_t)4 * 256 * 4096) * 2;

  qkv_proj<<<dim3(256, 5), 256, 0, stream>>>(x, Wq, bq, Wk, bk, Wv, bv, Qb, Kb, Vt);

  const size_t per_split = (size_t)4 * 4096 * 256 * 2 + (size_t)4 * 4096 * 4 * 2;
  int S = 1;
  if (ws_size >= base_bytes + 4 * per_split) S = 4;
  else if (ws_size >= base_bytes + 2 * per_split) S = 2;

  unsigned short* Oc = Vt;  // dead after attn; 8MB exactly

  if (S == 4) {
    float* Mp = (float*)(Op + (size_t)4 * 4 * 4096 * 256);
    float* Lp = Mp + (size_t)4 * 4 * 4096;
    attn_fwd<4><<<dim3(32, 4, 4), 512, 0, stream>>>(Qb, Kb, Vt, Op, Mp, Lp);
    combine_o<4><<<2048, 256, 0, stream>>>(Op, Mp, Lp, Oc);
  } else if (S == 2) {
    float* Mp = (float*)(Op + (size_t)2 * 4 * 4096 * 256);
    float* Lp = Mp + (size_t)2 * 4 * 4096;
    attn_fwd<2><<<dim3(32, 4, 2), 512, 0, stream>>>(Qb, Kb, Vt, Op, Mp, Lp);
    combine_o<2><<<2048, 256, 0, stream>>>(Op, Mp, Lp, Oc);
  } else {
    float* Mp = (float*)(Op + (size_t)1 * 4 * 4096 * 256);
    float* Lp = Mp + (size_t)1 * 4 * 4096;
    attn_fwd<1><<<dim3(32, 4, 1), 512, 0, stream>>>(Qb, Kb, Vt, Op, Mp, Lp);
    combine_o<1><<<2048, 256, 0, stream>>>(Op, Mp, Lp, Oc);
  }
  out_proj<<<dim3(256, 4), 256, 0, stream>>>(Oc, Wp, bp, x, gm, y);
}